// Round 10
// baseline (218.448 us; speedup 1.0000x reference)
//
#include <hip/hip_runtime.h>
#include <hip/hip_bf16.h>

// Problem constants (B=2, S=2048, D=1024, H=16, Dh=64) — I/O float32.
#define BB 2
#define SS 2048
#define DD 1024
#define HH 16
#define N3 3072

// split-K partial buffer geometry: [half][bh(32)][tile-16(16)][row(64)][d(64)]
#define POH (32 * 16 * 64 * 64)   // floats per half = 2,097,152
#define PLH (32 * 16 * 64)        // l floats per half = 32,768

typedef __attribute__((ext_vector_type(8))) short bf16x8;   // 8 bf16 in 4 VGPRs
typedef __attribute__((ext_vector_type(4))) float f32x4;
typedef __attribute__((ext_vector_type(2))) unsigned int u32x2;

__device__ __forceinline__ float b2f(unsigned short u) {
    return __uint_as_float(((unsigned int)u) << 16);
}
__device__ __forceinline__ unsigned short f2b(float f) {
    unsigned int x = __float_as_uint(f);
    x += 0x7fffu + ((x >> 16) & 1u);   // RNE
    return (unsigned short)(x >> 16);
}
__device__ __forceinline__ unsigned int pack2bf(float a, float b) {
    __hip_bfloat162 h = __float22bfloat162_rn(make_float2(a, b));  // v_cvt_pk_bf16_f32
    return *(unsigned int*)&h;
}
__device__ __forceinline__ void storeC(float* p, float v) { *p = v; }
__device__ __forceinline__ void storeC(unsigned short* p, float v) { *p = f2b(v); }

// async global->LDS, 16B/lane; LDS dest = wave-uniform base + lane*16.
__device__ __forceinline__ void gload_lds16(const void* g, void* l) {
    __builtin_amdgcn_global_load_lds(
        (__attribute__((address_space(1))) void*)g,
        (__attribute__((address_space(3))) void*)l, 16, 0, 0);
}

// ---------------------------------------------------------------------------
// sin/cos table: tab[s][t] = (cos, sin)(s * 10000^(-t/32)), fp32.
// ---------------------------------------------------------------------------
__global__ __launch_bounds__(256) void sincos_tab(float2* __restrict__ tab) {
    int i = blockIdx.x * 256 + threadIdx.x;   // SS*32
    int t = i & 31;
    int s = i >> 5;
    float inv = powf(10000.0f, -(float)t * (1.0f / 32.0f));
    float sn, c;
    sincosf((float)s * inv, &sn, &c);
    tab[i] = make_float2(c, sn);
}

// ---------------------------------------------------------------------------
// fp32 -> bf16 elementwise cast.
// ---------------------------------------------------------------------------
__global__ __launch_bounds__(256) void cast_f32_bf16(
    const float* __restrict__ src, unsigned short* __restrict__ dst)
{
    int i = (blockIdx.x * 256 + threadIdx.x) * 4;
    float4 f = *(const float4*)(src + i);
    uint2 o;
    o.x = pack2bf(f.x, f.y);
    o.y = pack2bf(f.z, f.w);
    *(uint2*)(dst + i) = o;
}

// ---------------------------------------------------------------------------
// fp32 [R][C] -> bf16 [C][R] cast + transpose. 64x64 tile / 256 threads.
// ---------------------------------------------------------------------------
__global__ __launch_bounds__(256) void cast_transpose(
    const float* __restrict__ src, unsigned short* __restrict__ dst,
    int R, int C)
{
    __shared__ unsigned short tile[64][66];
    const int t = threadIdx.x;
    const int c0 = blockIdx.x * 64, r0 = blockIdx.y * 64;
    const int lr = t >> 4;
    const int lc = (t & 15) * 4;
    #pragma unroll
    for (int i = 0; i < 4; ++i) {
        float4 f = *(const float4*)(src + (size_t)(r0 + lr + i * 16) * C + c0 + lc);
        tile[lr + i * 16][lc + 0] = f2b(f.x);
        tile[lr + i * 16][lc + 1] = f2b(f.y);
        tile[lr + i * 16][lc + 2] = f2b(f.z);
        tile[lr + i * 16][lc + 3] = f2b(f.w);
    }
    __syncthreads();
    #pragma unroll
    for (int i = 0; i < 4; ++i) {
        const int wr = lr + i * 16;
        ushort4 o;
        o.x = tile[lc + 0][wr];
        o.y = tile[lc + 1][wr];
        o.z = tile[lc + 2][wr];
        o.w = tile[lc + 3][wr];
        *(ushort4*)(dst + (size_t)(c0 + wr) * R + r0 + lc) = o;
    }
}

// ---------------------------------------------------------------------------
// bf16 MFMA GEMM: C[M,N] = A[M,K] @ Bt[N,K]^T. Tile 128 x TN, BK=32, 4 waves.
// ---------------------------------------------------------------------------
template <typename OutT, int TN>
__global__ __launch_bounds__(256) void gemm_mfma(
    const unsigned short* __restrict__ A,
    const unsigned short* __restrict__ Bt,
    OutT* __restrict__ C,
    int M, int N, int K)
{
    constexpr int NI = TN / 32;
    constexpr int NB = TN / 64;
    __shared__ unsigned short Al[128 * 32];
    __shared__ unsigned short Bl[TN * 32];
    const int tid  = threadIdx.x;
    const int wave = tid >> 6;
    const int lane = tid & 63;
    const int quad = lane >> 4;
    const int l16  = lane & 15;
    const int m0 = blockIdx.y * 128;
    const int n0 = blockIdx.x * TN;
    const int wm = (wave >> 1) * 64;
    const int wn = (wave & 1) * (TN / 2);

    const int srowA = wave * 32 + (lane >> 2);
    const int srowB = wave * (16 * NB) + (lane >> 2);
    const int scol  = (lane & 3) * 8;
    const unsigned short* gA = A  + (size_t)(m0 + srowA) * K + scol;
    const unsigned short* gB = Bt + (size_t)(n0 + srowB) * K + scol;

    f32x4 acc[4][NI];
    #pragma unroll
    for (int mi = 0; mi < 4; ++mi)
        #pragma unroll
        for (int ni = 0; ni < NI; ++ni)
            acc[mi][ni] = (f32x4){0.f, 0.f, 0.f, 0.f};

    for (int k0 = 0; k0 < K; k0 += 32) {
        __syncthreads();
        #pragma unroll
        for (int i = 0; i < 2; ++i)
            gload_lds16(gA + (size_t)i * 16 * K + k0, Al + (wave * 2 + i) * 512);
        #pragma unroll
        for (int i = 0; i < NB; ++i)
            gload_lds16(gB + (size_t)i * 16 * K + k0, Bl + (wave * NB + i) * 512);
        __syncthreads();

        bf16x8 af[4], bfr[NI];
        #pragma unroll
        for (int mi = 0; mi < 4; ++mi)
            af[mi] = *(const bf16x8*)&Al[(wm + mi * 16 + l16) * 32 + quad * 8];
        #pragma unroll
        for (int ni = 0; ni < NI; ++ni)
            bfr[ni] = *(const bf16x8*)&Bl[(wn + ni * 16 + l16) * 32 + quad * 8];
        #pragma unroll
        for (int mi = 0; mi < 4; ++mi)
            #pragma unroll
            for (int ni = 0; ni < NI; ++ni)
                acc[mi][ni] = __builtin_amdgcn_mfma_f32_16x16x32_bf16(
                    af[mi], bfr[ni], acc[mi][ni], 0, 0, 0);
    }

    #pragma unroll
    for (int mi = 0; mi < 4; ++mi) {
        #pragma unroll
        for (int r = 0; r < 4; ++r) {
            const size_t base = (size_t)(m0 + wm + mi * 16 + quad * 4 + r) * N + n0 + wn;
            #pragma unroll
            for (int ni = 0; ni < NI; ++ni)
                storeC(&C[base + ni * 16 + l16], acc[mi][ni][r]);
        }
    }
}

// ---------------------------------------------------------------------------
// GEMM1 + fused RoPE/split/V-transpose epilogue.
// C = xb @ w1t^T (M=4096, N=3072, K=1024), tile 128x128. With TN=128 each
// wave's 64-col output window is 64-aligned -> exactly ONE head and ONE
// section (q/k/v). Lane holds both rotation partners: d = ni*16+l16 in
// acc[mi][ni], d+32 in acc[mi][ni+2] (ni<2). Rotate from f32 accumulators,
// scale q by 0.125*log2e, store q,k -> [B,H,S,64]; v -> vt [B,H,64,S] as
// ushort4 over r (4 consecutive s). Eliminates the qkv intermediate entirely.
// ---------------------------------------------------------------------------
__global__ __launch_bounds__(256) void gemm_qkv_rope(
    const unsigned short* __restrict__ A,     // xb [4096][1024]
    const unsigned short* __restrict__ Bt,    // w1t [3072][1024]
    const float2* __restrict__ tab,
    unsigned short* __restrict__ qo,
    unsigned short* __restrict__ ko,
    unsigned short* __restrict__ vt)
{
    constexpr int K = DD;
    __shared__ unsigned short Al[128 * 32];
    __shared__ unsigned short Bl[128 * 32];
    const int tid  = threadIdx.x;
    const int wave = tid >> 6;
    const int lane = tid & 63;
    const int quad = lane >> 4;
    const int l16  = lane & 15;
    const int m0 = blockIdx.y * 128;
    const int n0 = blockIdx.x * 128;
    const int wm = (wave >> 1) * 64;
    const int wn = (wave & 1) * 64;

    const int srow = wave * 32 + (lane >> 2);
    const int scol = (lane & 3) * 8;
    const unsigned short* gA = A  + (size_t)(m0 + srow) * K + scol;
    const unsigned short* gB = Bt + (size_t)(n0 + srow) * K + scol;

    f32x4 acc[4][4];
    #pragma unroll
    for (int mi = 0; mi < 4; ++mi)
        #pragma unroll
        for (int ni = 0; ni < 4; ++ni)
            acc[mi][ni] = (f32x4){0.f, 0.f, 0.f, 0.f};

    for (int k0 = 0; k0 < K; k0 += 32) {
        __syncthreads();
        #pragma unroll
        for (int i = 0; i < 2; ++i) {
            gload_lds16(gA + (size_t)i * 16 * K + k0, Al + (wave * 2 + i) * 512);
            gload_lds16(gB + (size_t)i * 16 * K + k0, Bl + (wave * 2 + i) * 512);
        }
        __syncthreads();

        bf16x8 af[4], bfr[4];
        #pragma unroll
        for (int mi = 0; mi < 4; ++mi)
            af[mi] = *(const bf16x8*)&Al[(wm + mi * 16 + l16) * 32 + quad * 8];
        #pragma unroll
        for (int ni = 0; ni < 4; ++ni)
            bfr[ni] = *(const bf16x8*)&Bl[(wn + ni * 16 + l16) * 32 + quad * 8];
        #pragma unroll
        for (int mi = 0; mi < 4; ++mi)
            #pragma unroll
            for (int ni = 0; ni < 4; ++ni)
                acc[mi][ni] = __builtin_amdgcn_mfma_f32_16x16x32_bf16(
                    af[mi], bfr[ni], acc[mi][ni], 0, 0, 0);
    }

    // fused epilogue
    const int gc  = n0 + wn;                 // 64-aligned global col base
    const int sec = gc >> 10;                // 0=q, 1=k, 2=v
    const int h   = (gc & 1023) >> 6;
    const int s0g = m0 + wm;
    const int b   = s0g >> 11;               // tile within one batch
    const size_t bh = (size_t)b * HH + h;

    if (sec < 2) {
        const float SCq = (sec == 0) ? 0.18033688011112042f : 1.0f;  // 0.125*log2e on q
        unsigned short* dst = (sec == 0) ? qo : ko;
        #pragma unroll
        for (int mi = 0; mi < 4; ++mi) {
            #pragma unroll
            for (int r = 0; r < 4; ++r) {
                const int ss = (s0g + mi * 16 + quad * 4 + r) & (SS - 1);
                const float2* tp = tab + (size_t)ss * 32;
                unsigned short* row = dst + (bh * SS + ss) * 64;
                #pragma unroll
                for (int ni = 0; ni < 2; ++ni) {
                    const int t = ni * 16 + l16;       // d < 32, freq index
                    float2 cs = tp[t];                 // coalesced over l16
                    const float x1 = acc[mi][ni][r];
                    const float x2 = acc[mi][ni + 2][r];
                    row[t]      = f2b((x1 * cs.x - x2 * cs.y) * SCq);
                    row[t + 32] = f2b((x1 * cs.y + x2 * cs.x) * SCq);
                }
            }
        }
    } else {
        #pragma unroll
        for (int mi = 0; mi < 4; ++mi) {
            const int ss0 = (s0g + mi * 16 + quad * 4) & (SS - 1);
            #pragma unroll
            for (int ni = 0; ni < 4; ++ni) {
                const int d = ni * 16 + l16;
                ushort4 o;
                o.x = f2b(acc[mi][ni][0]);
                o.y = f2b(acc[mi][ni][1]);
                o.z = f2b(acc[mi][ni][2]);
                o.w = f2b(acc[mi][ni][3]);
                *(ushort4*)(vt + (bh * 64 + d) * SS + ss0) = o;   // 8B aligned
            }
        }
    }
}

// ---------------------------------------------------------------------------
// One 64-key attention step (v9 math): max-free softmax (P = exp2(S) directly,
// normalization cancels the row scale exactly) + in-register P redistribution
// via permlane32/16 swaps + ones-MFMA l reduction. T5 setprio around the MFMA
// clusters (independent blocks at different phases -> scheduler can arbitrate).
// ---------------------------------------------------------------------------
__device__ __forceinline__ void attn_step(
    const unsigned short* __restrict__ Kb,   // K tile [key][64], swizzled
    const unsigned short* __restrict__ Vb,   // V^T tile [d][64], swizzled
    const bf16x8 qf0, const bf16x8 qf1, const bf16x8 onesf,
    f32x4 O[4], f32x4& l_acc,
    bool diag, const unsigned char* mrow,    // mrow != nullptr => non-causal mask
    int kt, int quad, int l16, int csw, int qg)
{
    // S^T = K·Q^T : 4 key-subtiles (scale folded into q)
    f32x4 Sf[4];
    __builtin_amdgcn_s_setprio(1);
    #pragma unroll
    for (int st = 0; st < 4; ++st) {
        const unsigned short* kr = &Kb[(st * 16 + l16) * 64];
        bf16x8 kf0 = *(const bf16x8*)(kr + csw * 8);
        bf16x8 kf1 = *(const bf16x8*)(kr + (csw ^ 4) * 8);
        f32x4 s = (f32x4){0.f, 0.f, 0.f, 0.f};
        s = __builtin_amdgcn_mfma_f32_16x16x32_bf16(kf0, qf0, s, 0, 0, 0);
        s = __builtin_amdgcn_mfma_f32_16x16x32_bf16(kf1, qf1, s, 0, 0, 0);
        Sf[st] = s;
    }
    __builtin_amdgcn_s_setprio(0);

    if (diag) {
        #pragma unroll
        for (int st = 0; st < 4; ++st) {
            const int kb0 = kt * 64 + st * 16 + quad * 4;
            #pragma unroll
            for (int r = 0; r < 4; ++r)
                if (kb0 + r > qg) Sf[st][r] = -1e30f;
        }
    } else if (mrow) {
        #pragma unroll
        for (int st = 0; st < 4; ++st) {
            uchar4 mv = *(const uchar4*)(mrow + st * 16 + quad * 4);
            if (!mv.x) Sf[st][0] = -1e30f;
            if (!mv.y) Sf[st][1] = -1e30f;
            if (!mv.z) Sf[st][2] = -1e30f;
            if (!mv.w) Sf[st][3] = -1e30f;
        }
    }

    // P = exp2(S) directly (masked lanes -> exp2(-1e30) = 0)
    #pragma unroll
    for (int st = 0; st < 4; ++st)
        #pragma unroll
        for (int r = 0; r < 4; ++r)
            Sf[st][r] = exp2f(Sf[st][r]);

    // pack: W[st][j] = bf16 pair of keys (st*16+quad*4+2j, +1)
    unsigned int W[4][2];
    #pragma unroll
    for (int st = 0; st < 4; ++st) {
        W[st][0] = pack2bf(Sf[st][0], Sf[st][1]);
        W[st][1] = pack2bf(Sf[st][2], Sf[st][3]);
    }

    // in-register quad exchange -> PV B-operand fragments
    unsigned int pw0[4], pw1[4];
    #pragma unroll
    for (int j = 0; j < 2; ++j) {
        u32x2 s1 = __builtin_amdgcn_permlane32_swap(W[0][j], W[1][j], false, false);
        u32x2 s2 = __builtin_amdgcn_permlane16_swap(s1.x, s1.y, false, false);
        pw0[j]     = s2.x;
        pw0[j + 2] = s2.y;
        u32x2 t1 = __builtin_amdgcn_permlane32_swap(W[2][j], W[3][j], false, false);
        u32x2 t2 = __builtin_amdgcn_permlane16_swap(t1.x, t1.y, false, false);
        pw1[j]     = t2.x;
        pw1[j + 2] = t2.y;
    }
    bf16x8 pf0 = *(const bf16x8*)pw0;
    bf16x8 pf1 = *(const bf16x8*)pw1;

    // l += 1^T · P^T ; O^T += V^T·P^T  (matrix pipe)
    __builtin_amdgcn_s_setprio(1);
    l_acc = __builtin_amdgcn_mfma_f32_16x16x32_bf16(onesf, pf0, l_acc, 0, 0, 0);
    l_acc = __builtin_amdgcn_mfma_f32_16x16x32_bf16(onesf, pf1, l_acc, 0, 0, 0);
    #pragma unroll
    for (int st = 0; st < 4; ++st) {
        const unsigned short* vr = &Vb[(st * 16 + l16) * 64];
        bf16x8 vf0 = *(const bf16x8*)(vr + csw * 8);
        bf16x8 vf1 = *(const bf16x8*)(vr + (csw ^ 4) * 8);
        O[st] = __builtin_amdgcn_mfma_f32_16x16x32_bf16(vf0, pf0, O[st], 0, 0, 0);
        O[st] = __builtin_amdgcn_mfma_f32_16x16x32_bf16(vf1, pf1, O[st], 0, 0, 0);
    }
    __builtin_amdgcn_s_setprio(0);
}

// ---------------------------------------------------------------------------
// Flash attention v14: ATOMIC-FREE split-K. Max-free softmax makes partials
// exactly additive, and each split tile has exactly TWO jobs (A-half keys
// 0..15, B-half keys 16..tile) -> each half writes its own disjoint partial
// buffer with plain coalesced f32x4 stores; no atomics, no zeroing pass.
// Per (b,h): 48 jobs, MAX JOB = 16 trips (halves the per-CU makespan vs the
// 32-trip monolithic tile). LPT issue order inside XCD chunks; 1536 blocks,
// LDS 32 KB -> 5 resident blocks/CU + backfill. v9 per-step math + T5 setprio.
// q,k: [B,H,S,64] bf16 (q pre-scaled); vt: [B,H,64,S] bf16; y: [B,S,H*64] bf16.
// ---------------------------------------------------------------------------
__global__ __launch_bounds__(256) void flash_attn(
    const unsigned short* __restrict__ q,
    const unsigned short* __restrict__ k,
    const unsigned short* __restrict__ vt,
    unsigned short* __restrict__ y,
    float* __restrict__ pO,                  // [2][bh][tile-16][row64][d64] f32
    float* __restrict__ pL,                  // [2][bh][tile-16][row64] f32
    const int* __restrict__ is_causal,
    const unsigned char* __restrict__ attn_mask)
{
    __shared__ unsigned short Kl[2][64 * 64];
    __shared__ unsigned short Vl[2][64 * 64];

    // XCD chunk = 192 consecutive works = 4 (b,h) x 48 jobs, LPT order.
    const int bid  = blockIdx.x;                   // 0..1535
    const int work = (bid & 7) * 192 + (bid >> 3);
    const int bhi  = work / 48;                    // 0..31 = b*16+h
    const int s    = work % 48;                    // job slot, descending trips
    const int b = bhi >> 4;
    const int h = bhi & 15;
    const bool causal = (is_causal[0] != 0);

    // job decode: s<16 -> A-half of tile 16+s (keys 0..15, 16 trips).
    // s>=16, r=s-16, p=r>>1: r odd -> whole tile 15-p; r even -> B-half of
    // tile 31-p (keys 16..tile). Descending-trip issue order.
    int tile, k0t, k1t;
    bool split;
    if (s < 16) {
        tile = 16 + s; k0t = 0; k1t = 15; split = true;
    } else {
        const int r = s - 16, p = r >> 1;
        if (r & 1) { tile = 15 - p; k0t = 0;  k1t = causal ? tile : 31; split = false; }
        else       { tile = 31 - p; k0t = 16; k1t = causal ? tile : 31; split = true;  }
    }
    const int half = (s < 16) ? 0 : 1;             // A-partials : B-partials

    const int tid  = threadIdx.x;
    const int wave = tid >> 6;
    const int lane = tid & 63;
    const int quad = lane >> 4;
    const int l16  = lane & 15;

    const size_t bh = (size_t)b * HH + h;

    const int qg = tile * 64 + wave * 16 + l16;
    const unsigned short* qrow = q + (bh * SS + qg) * 64;
    const bf16x8 qf0 = *(const bf16x8*)(qrow + quad * 8);
    const bf16x8 qf1 = *(const bf16x8*)(qrow + 32 + quad * 8);

    bf16x8 onesf;
    #pragma unroll
    for (int i = 0; i < 8; ++i) onesf[i] = (short)0x3F80;   // bf16 1.0

    const unsigned short* kbase  = k  + bh * SS * 64;   // [key][d]
    const unsigned short* vtbase = vt + bh * 64 * SS;   // [d][s]

    const int Rl  = lane >> 3;
    const int cph = lane & 7;
    const int csw = quad ^ (l16 & 7);

    f32x4 O[4];
    #pragma unroll
    for (int st = 0; st < 4; ++st) O[st] = (f32x4){0.f, 0.f, 0.f, 0.f};
    f32x4 l_acc = (f32x4){0.f, 0.f, 0.f, 0.f};

    // stage K/V tile kt into buffer kt&1 (4 issues per wave)
    auto stage = [&](int kt) {
        const int buf = kt & 1;
        #pragma unroll
        for (int i = 0; i < 2; ++i) {
            const int jj = wave * 2 + i;
            const int R  = jj * 8 + Rl;
            const int cl = cph ^ (R & 7);
            gload_lds16(kbase + ((size_t)(kt * 64 + R) * 64 + cl * 8),
                        &Kl[buf][jj * 512]);
            gload_lds16(vtbase + ((size_t)R * SS + kt * 64 + cl * 8),
                        &Vl[buf][jj * 512]);
        }
    };

    stage(k0t);
    for (int kt = k0t; kt <= k1t; ++kt) {
        __syncthreads();                     // stage(kt) visible; prev reads done
        if (kt + 1 <= k1t) stage(kt + 1);    // prefetch into other buffer

        const unsigned char* mrow = causal ? nullptr
                                           : (attn_mask + (size_t)b * SS + kt * 64);
        attn_step(Kl[kt & 1], Vl[kt & 1], qf0, qf1, onesf, O, l_acc,
                  causal && kt == tile, mrow, kt, quad, l16, csw, qg);
    }

    if (!split) {
        // whole-tile job: l_acc fully reduced; normalize and store bf16.
        const float inv = 1.0f / l_acc[0];
        unsigned short* yrow = y + ((size_t)b * SS + qg) * DD + h * 64;
        #pragma unroll
        for (int st = 0; st < 4; ++st) {
            uint2 o;
            o.x = pack2bf(O[st][0] * inv, O[st][1] * inv);
            o.y = pack2bf(O[st][2] * inv, O[st][3] * inv);
            *(uint2*)(yrow + st * 16 + quad * 4) = o;
        }
    } else {
        // split job: plain stores into this half's disjoint partial buffer.
        float* ob = pO + (size_t)half * POH
                  + (((bh * 16 + (size_t)(tile - 16)) * 64 + wave * 16 + l16) * 64);
        #pragma unroll
        for (int st = 0; st < 4; ++st)
            *(f32x4*)(ob + st * 16 + quad * 4) = O[st];
        if (quad == 0)
            pL[(size_t)half * PLH + (bh * 16 + (size_t)(tile - 16)) * 64
               + wave * 16 + l16] = l_acc[0];
    }
}

// ---------------------------------------------------------------------------
// Merge split-K halves: y rows of tiles 16..31 = (O_A+O_B)/(l_A+l_B), bf16.
// One thread per 4 floats of a half (2,097,152 floats -> 2048 blocks x 256).
// ---------------------------------------------------------------------------
__global__ __launch_bounds__(256) void attn_merge(
    const float* __restrict__ pO, const float* __restrict__ pL,
    unsigned short* __restrict__ y)
{
    const int i = (blockIdx.x * 256 + threadIdx.x) * 4;
    float4 oa = *(const float4*)(pO + i);
    float4 obv = *(const float4*)(pO + POH + i);
    const int rowi = i >> 6;            // (bh*16+tt)*64 + row
    const int d    = i & 63;
    const float inv = 1.0f / (pL[rowi] + pL[PLH + rowi]);
    const int row = rowi & 63;
    const int tt  = (rowi >> 6) & 15;
    const int bh  = rowi >> 10;
    const int b = bh >> 4, h = bh & 15;
    const int sq = (16 + tt) * 64 + row;
    unsigned short* yp = y + ((size_t)b * SS + sq) * DD + h * 64 + d;
    uint2 ov;
    ov.x = pack2bf((oa.x + obv.x) * inv, (oa.y + obv.y) * inv);
    ov.y = pack2bf((oa.z + obv.z) * inv, (oa.w + obv.w) * inv);
    *(uint2*)yp = ov;
}

// ---------------------------------------------------------------------------
// Workspace: xb/yb (aliased) | w1t | w2t | pO/pL (old qkv region) | qb | kb |
// vt | tab. ~67.6 MB.
// ---------------------------------------------------------------------------
extern "C" void kernel_launch(void* const* d_in, const int* in_sizes, int n_in,
                              void* d_out, int out_size, void* d_ws, size_t ws_size,
                              hipStream_t stream) {
    const float* x      = (const float*)d_in[0];
    const float* qkv_w  = (const float*)d_in[1];
    const float* out_w  = (const float*)d_in[2];
    const unsigned char* mask = (const unsigned char*)d_in[3];
    const int*   is_c   = (const int*)d_in[4];
    float* out = (float*)d_out;

    unsigned short* xb  = (unsigned short*)d_ws;             // aliased with yb
    unsigned short* w1t = xb  + (size_t)4096 * 1024;
    unsigned short* w2t = w1t + (size_t)3072 * 1024;
    unsigned short* qkv = w2t + (size_t)1024 * 1024;         // region: pO/pL
    unsigned short* qb  = qkv + (size_t)4096 * 3072;
    unsigned short* kb  = qb  + (size_t)BB * HH * SS * 64;
    unsigned short* vt  = kb  + (size_t)BB * HH * SS * 64;
    float2* tab = (float2*)(vt + (size_t)BB * HH * SS * 64);
    unsigned short* yb = xb;   // x dead after GEMM1

    // split-K partials in the old qkv region (never written otherwise now):
    // 2*POH + 2*PLH floats = 17.0 MB < 25.2 MB available.
    float* pO = (float*)qkv;                 // [2][POH]
    float* pL = pO + (size_t)2 * POH;        // [2][PLH]

    sincos_tab<<<(SS * 32) / 256, 256, 0, stream>>>(tab);
    cast_f32_bf16<<<(4096 * 1024) / 1024, 256, 0, stream>>>(x, xb);
    cast_transpose<<<dim3(N3 / 64, DD / 64), 256, 0, stream>>>(qkv_w, w1t, DD, N3);
    cast_transpose<<<dim3(DD / 64, DD / 64), 256, 0, stream>>>(out_w, w2t, DD, DD);

    // GEMM1 + fused RoPE/split/V-transpose: writes qb, kb, vt directly.
    gemm_qkv_rope<<<dim3(N3 / 128, 4096 / 128), 256, 0, stream>>>(
        xb, w1t, tab, qb, kb, vt);

    // Flash attention v14 (atomic-free split-K, max job 16 trips, LPT order)
    flash_attn<<<dim3(48 * BB * HH), 256, 0, stream>>>(qb, kb, vt, yb, pO, pL,
                                                       is_c, mask);

    // merge halves into y rows 1024..2047 per batch
    attn_merge<<<2048, 256, 0, stream>>>(pO, pL, yb);

    // GEMM2: out = y @ out_w  (M=4096, N=1024, K=1024), tile 128x128 -> 256 blocks
    gemm_mfma<float, 128><<<dim3(DD / 128, 4096 / 128), 256, 0, stream>>>(
        yb, w2t, out, 4096, DD, DD);
}

// Round 11
// 195.944 us; speedup vs baseline: 1.1148x; 1.1148x over previous
//
#include <hip/hip_runtime.h>
#include <hip/hip_bf16.h>

// Problem constants (B=2, S=2048, D=1024, H=16, Dh=64) — I/O float32.
#define BB 2
#define SS 2048
#define DD 1024
#define HH 16
#define N3 3072

// split-K partial buffer geometry: [half][bh(32)][tile-16(16)][row(64)][d(64)]
#define POH (32 * 16 * 64 * 64)   // floats per half = 2,097,152
#define PLH (32 * 16 * 64)        // l floats per half = 32,768

typedef __attribute__((ext_vector_type(8))) short bf16x8;   // 8 bf16 in 4 VGPRs
typedef __attribute__((ext_vector_type(4))) float f32x4;
typedef __attribute__((ext_vector_type(2))) unsigned int u32x2;

__device__ __forceinline__ float b2f(unsigned short u) {
    return __uint_as_float(((unsigned int)u) << 16);
}
__device__ __forceinline__ unsigned short f2b(float f) {
    unsigned int x = __float_as_uint(f);
    x += 0x7fffu + ((x >> 16) & 1u);   // RNE
    return (unsigned short)(x >> 16);
}
__device__ __forceinline__ unsigned int pack2bf(float a, float b) {
    __hip_bfloat162 h = __float22bfloat162_rn(make_float2(a, b));  // v_cvt_pk_bf16_f32
    return *(unsigned int*)&h;
}
__device__ __forceinline__ void storeC(float* p, float v) { *p = v; }
__device__ __forceinline__ void storeC(unsigned short* p, float v) { *p = f2b(v); }

// async global->LDS, 16B/lane; LDS dest = wave-uniform base + lane*16.
__device__ __forceinline__ void gload_lds16(const void* g, void* l) {
    __builtin_amdgcn_global_load_lds(
        (__attribute__((address_space(1))) void*)g,
        (__attribute__((address_space(3))) void*)l, 16, 0, 0);
}

// ---------------------------------------------------------------------------
// sin/cos table: tab[s][t] = (cos, sin)(s * 10000^(-t/32)), fp32.
// ---------------------------------------------------------------------------
__global__ __launch_bounds__(256) void sincos_tab(float2* __restrict__ tab) {
    int i = blockIdx.x * 256 + threadIdx.x;   // SS*32
    int t = i & 31;
    int s = i >> 5;
    float inv = powf(10000.0f, -(float)t * (1.0f / 32.0f));
    float sn, c;
    sincosf((float)s * inv, &sn, &c);
    tab[i] = make_float2(c, sn);
}

// ---------------------------------------------------------------------------
// fp32 -> bf16 elementwise cast.
// ---------------------------------------------------------------------------
__global__ __launch_bounds__(256) void cast_f32_bf16(
    const float* __restrict__ src, unsigned short* __restrict__ dst)
{
    int i = (blockIdx.x * 256 + threadIdx.x) * 4;
    float4 f = *(const float4*)(src + i);
    uint2 o;
    o.x = pack2bf(f.x, f.y);
    o.y = pack2bf(f.z, f.w);
    *(uint2*)(dst + i) = o;
}

// ---------------------------------------------------------------------------
// fp32 [R][C] -> bf16 [C][R] cast + transpose. 64x64 tile / 256 threads.
// ---------------------------------------------------------------------------
__global__ __launch_bounds__(256) void cast_transpose(
    const float* __restrict__ src, unsigned short* __restrict__ dst,
    int R, int C)
{
    __shared__ unsigned short tile[64][66];
    const int t = threadIdx.x;
    const int c0 = blockIdx.x * 64, r0 = blockIdx.y * 64;
    const int lr = t >> 4;
    const int lc = (t & 15) * 4;
    #pragma unroll
    for (int i = 0; i < 4; ++i) {
        float4 f = *(const float4*)(src + (size_t)(r0 + lr + i * 16) * C + c0 + lc);
        tile[lr + i * 16][lc + 0] = f2b(f.x);
        tile[lr + i * 16][lc + 1] = f2b(f.y);
        tile[lr + i * 16][lc + 2] = f2b(f.z);
        tile[lr + i * 16][lc + 3] = f2b(f.w);
    }
    __syncthreads();
    #pragma unroll
    for (int i = 0; i < 4; ++i) {
        const int wr = lr + i * 16;
        ushort4 o;
        o.x = tile[lc + 0][wr];
        o.y = tile[lc + 1][wr];
        o.z = tile[lc + 2][wr];
        o.w = tile[lc + 3][wr];
        *(ushort4*)(dst + (size_t)(c0 + wr) * R + r0 + lc) = o;
    }
}

// ---------------------------------------------------------------------------
// bf16 MFMA GEMM: C[M,N] = A[M,K] @ Bt[N,K]^T. Tile 128 x TN, BK=32, 4 waves.
// v15: DOUBLE-BUFFERED staging (stage k+1 after the barrier, compute overlaps
// in-flight loads; 1 barrier/step) + 1D grid with XCD-chunked decode (each
// XCD owns consecutive 128-row A panels, cols fastest -> A L2-hot, B L3-hot).
// ---------------------------------------------------------------------------
template <typename OutT, int TN>
__global__ __launch_bounds__(256) void gemm_mfma(
    const unsigned short* __restrict__ A,
    const unsigned short* __restrict__ Bt,
    OutT* __restrict__ C,
    int M, int N, int K, int nbx)
{
    constexpr int NI = TN / 32;
    constexpr int NB = TN / 64;
    __shared__ unsigned short Al[2][128 * 32];
    __shared__ unsigned short Bl[2][TN * 32];
    const int tid  = threadIdx.x;
    const int wave = tid >> 6;
    const int lane = tid & 63;
    const int quad = lane >> 4;
    const int l16  = lane & 15;

    // 1D XCD-chunked decode: per-XCD contiguous idx range, cols fastest.
    const int per = gridDim.x >> 3;
    const int idx = (blockIdx.x & 7) * per + (blockIdx.x >> 3);
    const int m0 = (idx / nbx) * 128;
    const int n0 = (idx % nbx) * TN;
    const int wm = (wave >> 1) * 64;
    const int wn = (wave & 1) * (TN / 2);

    const int srowA = wave * 32 + (lane >> 2);
    const int srowB = wave * (16 * NB) + (lane >> 2);
    const int scol  = (lane & 3) * 8;
    const unsigned short* gA = A  + (size_t)(m0 + srowA) * K + scol;
    const unsigned short* gB = Bt + (size_t)(n0 + srowB) * K + scol;

    f32x4 acc[4][NI];
    #pragma unroll
    for (int mi = 0; mi < 4; ++mi)
        #pragma unroll
        for (int ni = 0; ni < NI; ++ni)
            acc[mi][ni] = (f32x4){0.f, 0.f, 0.f, 0.f};

    auto stage = [&](int k0, int buf) {
        #pragma unroll
        for (int i = 0; i < 2; ++i)
            gload_lds16(gA + (size_t)i * 16 * K + k0, Al[buf] + (wave * 2 + i) * 512);
        #pragma unroll
        for (int i = 0; i < NB; ++i)
            gload_lds16(gB + (size_t)i * 16 * K + k0, Bl[buf] + (wave * NB + i) * 512);
    };

    stage(0, 0);
    int cur = 0;
    for (int k0 = 0; k0 < K; k0 += 32) {
        __syncthreads();                       // stage(cur) visible; prev reads done
        if (k0 + 32 < K) stage(k0 + 32, cur ^ 1);

        bf16x8 af[4], bfr[NI];
        #pragma unroll
        for (int mi = 0; mi < 4; ++mi)
            af[mi] = *(const bf16x8*)&Al[cur][(wm + mi * 16 + l16) * 32 + quad * 8];
        #pragma unroll
        for (int ni = 0; ni < NI; ++ni)
            bfr[ni] = *(const bf16x8*)&Bl[cur][(wn + ni * 16 + l16) * 32 + quad * 8];
        #pragma unroll
        for (int mi = 0; mi < 4; ++mi)
            #pragma unroll
            for (int ni = 0; ni < NI; ++ni)
                acc[mi][ni] = __builtin_amdgcn_mfma_f32_16x16x32_bf16(
                    af[mi], bfr[ni], acc[mi][ni], 0, 0, 0);
        cur ^= 1;
    }

    #pragma unroll
    for (int mi = 0; mi < 4; ++mi) {
        #pragma unroll
        for (int r = 0; r < 4; ++r) {
            const size_t base = (size_t)(m0 + wm + mi * 16 + quad * 4 + r) * N + n0 + wn;
            #pragma unroll
            for (int ni = 0; ni < NI; ++ni)
                storeC(&C[base + ni * 16 + l16], acc[mi][ni][r]);
        }
    }
}

// ---------------------------------------------------------------------------
// GEMM1 + fused RoPE/split/V-transpose epilogue, v15 (dbuf + XCD decode).
// C = xb @ w1t^T (M=4096, N=3072, K=1024), tile 128x128. With TN=128 each
// wave's 64-col output window is 64-aligned -> exactly ONE head and ONE
// section (q/k/v). Lane holds both rotation partners: d = ni*16+l16 in
// acc[mi][ni], d+32 in acc[mi][ni+2] (ni<2). Rotate from f32 accumulators,
// scale q by 0.125*log2e, store q,k -> [B,H,S,64]; v -> vt [B,H,64,S].
// ---------------------------------------------------------------------------
__global__ __launch_bounds__(256) void gemm_qkv_rope(
    const unsigned short* __restrict__ A,     // xb [4096][1024]
    const unsigned short* __restrict__ Bt,    // w1t [3072][1024]
    const float2* __restrict__ tab,
    unsigned short* __restrict__ qo,
    unsigned short* __restrict__ ko,
    unsigned short* __restrict__ vt)
{
    constexpr int K = DD;
    constexpr int nbx = N3 / 128;              // 24
    __shared__ unsigned short Al[2][128 * 32];
    __shared__ unsigned short Bl[2][128 * 32];
    const int tid  = threadIdx.x;
    const int wave = tid >> 6;
    const int lane = tid & 63;
    const int quad = lane >> 4;
    const int l16  = lane & 15;

    const int per = gridDim.x >> 3;
    const int idx = (blockIdx.x & 7) * per + (blockIdx.x >> 3);
    const int m0 = (idx / nbx) * 128;
    const int n0 = (idx % nbx) * 128;
    const int wm = (wave >> 1) * 64;
    const int wn = (wave & 1) * 64;

    const int srow = wave * 32 + (lane >> 2);
    const int scol = (lane & 3) * 8;
    const unsigned short* gA = A  + (size_t)(m0 + srow) * K + scol;
    const unsigned short* gB = Bt + (size_t)(n0 + srow) * K + scol;

    f32x4 acc[4][4];
    #pragma unroll
    for (int mi = 0; mi < 4; ++mi)
        #pragma unroll
        for (int ni = 0; ni < 4; ++ni)
            acc[mi][ni] = (f32x4){0.f, 0.f, 0.f, 0.f};

    auto stage = [&](int k0, int buf) {
        #pragma unroll
        for (int i = 0; i < 2; ++i) {
            gload_lds16(gA + (size_t)i * 16 * K + k0, Al[buf] + (wave * 2 + i) * 512);
            gload_lds16(gB + (size_t)i * 16 * K + k0, Bl[buf] + (wave * 2 + i) * 512);
        }
    };

    stage(0, 0);
    int cur = 0;
    for (int k0 = 0; k0 < K; k0 += 32) {
        __syncthreads();                       // stage(cur) visible; prev reads done
        if (k0 + 32 < K) stage(k0 + 32, cur ^ 1);

        bf16x8 af[4], bfr[4];
        #pragma unroll
        for (int mi = 0; mi < 4; ++mi)
            af[mi] = *(const bf16x8*)&Al[cur][(wm + mi * 16 + l16) * 32 + quad * 8];
        #pragma unroll
        for (int ni = 0; ni < 4; ++ni)
            bfr[ni] = *(const bf16x8*)&Bl[cur][(wn + ni * 16 + l16) * 32 + quad * 8];
        #pragma unroll
        for (int mi = 0; mi < 4; ++mi)
            #pragma unroll
            for (int ni = 0; ni < 4; ++ni)
                acc[mi][ni] = __builtin_amdgcn_mfma_f32_16x16x32_bf16(
                    af[mi], bfr[ni], acc[mi][ni], 0, 0, 0);
        cur ^= 1;
    }

    // fused epilogue
    const int gc  = n0 + wn;                 // 64-aligned global col base
    const int sec = gc >> 10;                // 0=q, 1=k, 2=v
    const int h   = (gc & 1023) >> 6;
    const int s0g = m0 + wm;
    const int b   = s0g >> 11;               // batch
    const size_t bh = (size_t)b * HH + h;

    if (sec < 2) {
        const float SCq = (sec == 0) ? 0.18033688011112042f : 1.0f;  // 0.125*log2e on q
        unsigned short* dst = (sec == 0) ? qo : ko;
        #pragma unroll
        for (int mi = 0; mi < 4; ++mi) {
            #pragma unroll
            for (int r = 0; r < 4; ++r) {
                const int ss = (s0g + mi * 16 + quad * 4 + r) & (SS - 1);
                const float2* tp = tab + (size_t)ss * 32;
                unsigned short* row = dst + (bh * SS + ss) * 64;
                #pragma unroll
                for (int ni = 0; ni < 2; ++ni) {
                    const int t = ni * 16 + l16;       // d < 32, freq index
                    float2 cs = tp[t];                 // coalesced over l16
                    const float x1 = acc[mi][ni][r];
                    const float x2 = acc[mi][ni + 2][r];
                    row[t]      = f2b((x1 * cs.x - x2 * cs.y) * SCq);
                    row[t + 32] = f2b((x1 * cs.y + x2 * cs.x) * SCq);
                }
            }
        }
    } else {
        #pragma unroll
        for (int mi = 0; mi < 4; ++mi) {
            const int ss0 = (s0g + mi * 16 + quad * 4) & (SS - 1);
            #pragma unroll
            for (int ni = 0; ni < 4; ++ni) {
                const int d = ni * 16 + l16;
                ushort4 o;
                o.x = f2b(acc[mi][ni][0]);
                o.y = f2b(acc[mi][ni][1]);
                o.z = f2b(acc[mi][ni][2]);
                o.w = f2b(acc[mi][ni][3]);
                *(ushort4*)(vt + (bh * 64 + d) * SS + ss0) = o;   // 8B aligned
            }
        }
    }
}

// ---------------------------------------------------------------------------
// One 64-key attention step (v9 math): max-free softmax (P = exp2(S) directly,
// normalization cancels the row scale exactly) + in-register P redistribution
// via permlane32/16 swaps + ones-MFMA l reduction. T5 setprio around the MFMA
// clusters (independent blocks at different phases -> scheduler can arbitrate).
// ---------------------------------------------------------------------------
__device__ __forceinline__ void attn_step(
    const unsigned short* __restrict__ Kb,   // K tile [key][64], swizzled
    const unsigned short* __restrict__ Vb,   // V^T tile [d][64], swizzled
    const bf16x8 qf0, const bf16x8 qf1, const bf16x8 onesf,
    f32x4 O[4], f32x4& l_acc,
    bool diag, const unsigned char* mrow,    // mrow != nullptr => non-causal mask
    int kt, int quad, int l16, int csw, int qg)
{
    // S^T = K·Q^T : 4 key-subtiles (scale folded into q)
    f32x4 Sf[4];
    __builtin_amdgcn_s_setprio(1);
    #pragma unroll
    for (int st = 0; st < 4; ++st) {
        const unsigned short* kr = &Kb[(st * 16 + l16) * 64];
        bf16x8 kf0 = *(const bf16x8*)(kr + csw * 8);
        bf16x8 kf1 = *(const bf16x8*)(kr + (csw ^ 4) * 8);
        f32x4 s = (f32x4){0.f, 0.f, 0.f, 0.f};
        s = __builtin_amdgcn_mfma_f32_16x16x32_bf16(kf0, qf0, s, 0, 0, 0);
        s = __builtin_amdgcn_mfma_f32_16x16x32_bf16(kf1, qf1, s, 0, 0, 0);
        Sf[st] = s;
    }
    __builtin_amdgcn_s_setprio(0);

    if (diag) {
        #pragma unroll
        for (int st = 0; st < 4; ++st) {
            const int kb0 = kt * 64 + st * 16 + quad * 4;
            #pragma unroll
            for (int r = 0; r < 4; ++r)
                if (kb0 + r > qg) Sf[st][r] = -1e30f;
        }
    } else if (mrow) {
        #pragma unroll
        for (int st = 0; st < 4; ++st) {
            uchar4 mv = *(const uchar4*)(mrow + st * 16 + quad * 4);
            if (!mv.x) Sf[st][0] = -1e30f;
            if (!mv.y) Sf[st][1] = -1e30f;
            if (!mv.z) Sf[st][2] = -1e30f;
            if (!mv.w) Sf[st][3] = -1e30f;
        }
    }

    // P = exp2(S) directly (masked lanes -> exp2(-1e30) = 0)
    #pragma unroll
    for (int st = 0; st < 4; ++st)
        #pragma unroll
        for (int r = 0; r < 4; ++r)
            Sf[st][r] = exp2f(Sf[st][r]);

    // pack: W[st][j] = bf16 pair of keys (st*16+quad*4+2j, +1)
    unsigned int W[4][2];
    #pragma unroll
    for (int st = 0; st < 4; ++st) {
        W[st][0] = pack2bf(Sf[st][0], Sf[st][1]);
        W[st][1] = pack2bf(Sf[st][2], Sf[st][3]);
    }

    // in-register quad exchange -> PV B-operand fragments
    unsigned int pw0[4], pw1[4];
    #pragma unroll
    for (int j = 0; j < 2; ++j) {
        u32x2 s1 = __builtin_amdgcn_permlane32_swap(W[0][j], W[1][j], false, false);
        u32x2 s2 = __builtin_amdgcn_permlane16_swap(s1.x, s1.y, false, false);
        pw0[j]     = s2.x;
        pw0[j + 2] = s2.y;
        u32x2 t1 = __builtin_amdgcn_permlane32_swap(W[2][j], W[3][j], false, false);
        u32x2 t2 = __builtin_amdgcn_permlane16_swap(t1.x, t1.y, false, false);
        pw1[j]     = t2.x;
        pw1[j + 2] = t2.y;
    }
    bf16x8 pf0 = *(const bf16x8*)pw0;
    bf16x8 pf1 = *(const bf16x8*)pw1;

    // l += 1^T · P^T ; O^T += V^T·P^T  (matrix pipe)
    __builtin_amdgcn_s_setprio(1);
    l_acc = __builtin_amdgcn_mfma_f32_16x16x32_bf16(onesf, pf0, l_acc, 0, 0, 0);
    l_acc = __builtin_amdgcn_mfma_f32_16x16x32_bf16(onesf, pf1, l_acc, 0, 0, 0);
    #pragma unroll
    for (int st = 0; st < 4; ++st) {
        const unsigned short* vr = &Vb[(st * 16 + l16) * 64];
        bf16x8 vf0 = *(const bf16x8*)(vr + csw * 8);
        bf16x8 vf1 = *(const bf16x8*)(vr + (csw ^ 4) * 8);
        O[st] = __builtin_amdgcn_mfma_f32_16x16x32_bf16(vf0, pf0, O[st], 0, 0, 0);
        O[st] = __builtin_amdgcn_mfma_f32_16x16x32_bf16(vf1, pf1, O[st], 0, 0, 0);
    }
    __builtin_amdgcn_s_setprio(0);
}

// ---------------------------------------------------------------------------
// Flash attention v14: ATOMIC-FREE split-K. Max-free softmax makes partials
// exactly additive, and each split tile has exactly TWO jobs (A-half keys
// 0..15, B-half keys 16..tile) -> each half writes its own disjoint partial
// buffer with plain coalesced f32x4 stores; no atomics, no zeroing pass.
// Per (b,h): 48 jobs, MAX JOB = 16 trips (halves the per-CU makespan vs the
// 32-trip monolithic tile). LPT issue order inside XCD chunks; 1536 blocks,
// LDS 32 KB -> 5 resident blocks/CU + backfill. v9 per-step math + T5 setprio.
// q,k: [B,H,S,64] bf16 (q pre-scaled); vt: [B,H,64,S] bf16; y: [B,S,H*64] bf16.
// ---------------------------------------------------------------------------
__global__ __launch_bounds__(256) void flash_attn(
    const unsigned short* __restrict__ q,
    const unsigned short* __restrict__ k,
    const unsigned short* __restrict__ vt,
    unsigned short* __restrict__ y,
    float* __restrict__ pO,                  // [2][bh][tile-16][row64][d64] f32
    float* __restrict__ pL,                  // [2][bh][tile-16][row64] f32
    const int* __restrict__ is_causal,
    const unsigned char* __restrict__ attn_mask)
{
    __shared__ unsigned short Kl[2][64 * 64];
    __shared__ unsigned short Vl[2][64 * 64];

    // XCD chunk = 192 consecutive works = 4 (b,h) x 48 jobs, LPT order.
    const int bid  = blockIdx.x;                   // 0..1535
    const int work = (bid & 7) * 192 + (bid >> 3);
    const int bhi  = work / 48;                    // 0..31 = b*16+h
    const int s    = work % 48;                    // job slot, descending trips
    const int b = bhi >> 4;
    const int h = bhi & 15;
    const bool causal = (is_causal[0] != 0);

    // job decode: s<16 -> A-half of tile 16+s (keys 0..15, 16 trips).
    // s>=16, r=s-16, p=r>>1: r odd -> whole tile 15-p; r even -> B-half of
    // tile 31-p (keys 16..tile). Descending-trip issue order.
    int tile, k0t, k1t;
    bool split;
    if (s < 16) {
        tile = 16 + s; k0t = 0; k1t = 15; split = true;
    } else {
        const int r = s - 16, p = r >> 1;
        if (r & 1) { tile = 15 - p; k0t = 0;  k1t = causal ? tile : 31; split = false; }
        else       { tile = 31 - p; k0t = 16; k1t = causal ? tile : 31; split = true;  }
    }
    const int half = (s < 16) ? 0 : 1;             // A-partials : B-partials

    const int tid  = threadIdx.x;
    const int wave = tid >> 6;
    const int lane = tid & 63;
    const int quad = lane >> 4;
    const int l16  = lane & 15;

    const size_t bh = (size_t)b * HH + h;

    const int qg = tile * 64 + wave * 16 + l16;
    const unsigned short* qrow = q + (bh * SS + qg) * 64;
    const bf16x8 qf0 = *(const bf16x8*)(qrow + quad * 8);
    const bf16x8 qf1 = *(const bf16x8*)(qrow + 32 + quad * 8);

    bf16x8 onesf;
    #pragma unroll
    for (int i = 0; i < 8; ++i) onesf[i] = (short)0x3F80;   // bf16 1.0

    const unsigned short* kbase  = k  + bh * SS * 64;   // [key][d]
    const unsigned short* vtbase = vt + bh * 64 * SS;   // [d][s]

    const int Rl  = lane >> 3;
    const int cph = lane & 7;
    const int csw = quad ^ (l16 & 7);

    f32x4 O[4];
    #pragma unroll
    for (int st = 0; st < 4; ++st) O[st] = (f32x4){0.f, 0.f, 0.f, 0.f};
    f32x4 l_acc = (f32x4){0.f, 0.f, 0.f, 0.f};

    // stage K/V tile kt into buffer kt&1 (4 issues per wave)
    auto stage = [&](int kt) {
        const int buf = kt & 1;
        #pragma unroll
        for (int i = 0; i < 2; ++i) {
            const int jj = wave * 2 + i;
            const int R  = jj * 8 + Rl;
            const int cl = cph ^ (R & 7);
            gload_lds16(kbase + ((size_t)(kt * 64 + R) * 64 + cl * 8),
                        &Kl[buf][jj * 512]);
            gload_lds16(vtbase + ((size_t)R * SS + kt * 64 + cl * 8),
                        &Vl[buf][jj * 512]);
        }
    };

    stage(k0t);
    for (int kt = k0t; kt <= k1t; ++kt) {
        __syncthreads();                     // stage(kt) visible; prev reads done
        if (kt + 1 <= k1t) stage(kt + 1);    // prefetch into other buffer

        const unsigned char* mrow = causal ? nullptr
                                           : (attn_mask + (size_t)b * SS + kt * 64);
        attn_step(Kl[kt & 1], Vl[kt & 1], qf0, qf1, onesf, O, l_acc,
                  causal && kt == tile, mrow, kt, quad, l16, csw, qg);
    }

    if (!split) {
        // whole-tile job: l_acc fully reduced; normalize and store bf16.
        const float inv = 1.0f / l_acc[0];
        unsigned short* yrow = y + ((size_t)b * SS + qg) * DD + h * 64;
        #pragma unroll
        for (int st = 0; st < 4; ++st) {
            uint2 o;
            o.x = pack2bf(O[st][0] * inv, O[st][1] * inv);
            o.y = pack2bf(O[st][2] * inv, O[st][3] * inv);
            *(uint2*)(yrow + st * 16 + quad * 4) = o;
        }
    } else {
        // split job: plain stores into this half's disjoint partial buffer.
        float* ob = pO + (size_t)half * POH
                  + (((bh * 16 + (size_t)(tile - 16)) * 64 + wave * 16 + l16) * 64);
        #pragma unroll
        for (int st = 0; st < 4; ++st)
            *(f32x4*)(ob + st * 16 + quad * 4) = O[st];
        if (quad == 0)
            pL[(size_t)half * PLH + (bh * 16 + (size_t)(tile - 16)) * 64
               + wave * 16 + l16] = l_acc[0];
    }
}

// ---------------------------------------------------------------------------
// Merge split-K halves: y rows of tiles 16..31 = (O_A+O_B)/(l_A+l_B), bf16.
// One thread per 4 floats of a half (2,097,152 floats -> 2048 blocks x 256).
// ---------------------------------------------------------------------------
__global__ __launch_bounds__(256) void attn_merge(
    const float* __restrict__ pO, const float* __restrict__ pL,
    unsigned short* __restrict__ y)
{
    const int i = (blockIdx.x * 256 + threadIdx.x) * 4;
    float4 oa = *(const float4*)(pO + i);
    float4 obv = *(const float4*)(pO + POH + i);
    const int rowi = i >> 6;            // (bh*16+tt)*64 + row
    const int d    = i & 63;
    const float inv = 1.0f / (pL[rowi] + pL[PLH + rowi]);
    const int row = rowi & 63;
    const int tt  = (rowi >> 6) & 15;
    const int bh  = rowi >> 10;
    const int b = bh >> 4, h = bh & 15;
    const int sq = (16 + tt) * 64 + row;
    unsigned short* yp = y + ((size_t)b * SS + sq) * DD + h * 64 + d;
    uint2 ov;
    ov.x = pack2bf((oa.x + obv.x) * inv, (oa.y + obv.y) * inv);
    ov.y = pack2bf((oa.z + obv.z) * inv, (oa.w + obv.w) * inv);
    *(uint2*)yp = ov;
}

// ---------------------------------------------------------------------------
// Workspace: xb/yb (aliased) | w1t | w2t | pO/pL (old qkv region) | qb | kb |
// vt | tab. ~67.6 MB.
// ---------------------------------------------------------------------------
extern "C" void kernel_launch(void* const* d_in, const int* in_sizes, int n_in,
                              void* d_out, int out_size, void* d_ws, size_t ws_size,
                              hipStream_t stream) {
    const float* x      = (const float*)d_in[0];
    const float* qkv_w  = (const float*)d_in[1];
    const float* out_w  = (const float*)d_in[2];
    const unsigned char* mask = (const unsigned char*)d_in[3];
    const int*   is_c   = (const int*)d_in[4];
    float* out = (float*)d_out;

    unsigned short* xb  = (unsigned short*)d_ws;             // aliased with yb
    unsigned short* w1t = xb  + (size_t)4096 * 1024;
    unsigned short* w2t = w1t + (size_t)3072 * 1024;
    unsigned short* qkv = w2t + (size_t)1024 * 1024;         // region: pO/pL
    unsigned short* qb  = qkv + (size_t)4096 * 3072;
    unsigned short* kb  = qb  + (size_t)BB * HH * SS * 64;
    unsigned short* vt  = kb  + (size_t)BB * HH * SS * 64;
    float2* tab = (float2*)(vt + (size_t)BB * HH * SS * 64);
    unsigned short* yb = xb;   // x dead after GEMM1

    // split-K partials in the old qkv region (never written otherwise now):
    // 2*POH + 2*PLH floats = 17.0 MB < 25.2 MB available.
    float* pO = (float*)qkv;                 // [2][POH]
    float* pL = pO + (size_t)2 * POH;        // [2][PLH]

    sincos_tab<<<(SS * 32) / 256, 256, 0, stream>>>(tab);
    cast_f32_bf16<<<(4096 * 1024) / 1024, 256, 0, stream>>>(x, xb);
    cast_transpose<<<dim3(N3 / 64, DD / 64), 256, 0, stream>>>(qkv_w, w1t, DD, N3);
    cast_transpose<<<dim3(DD / 64, DD / 64), 256, 0, stream>>>(out_w, w2t, DD, DD);

    // GEMM1 + fused RoPE/split/V-transpose (dbuf, XCD-chunked 1D grid)
    gemm_qkv_rope<<<(N3 / 128) * (4096 / 128), 256, 0, stream>>>(
        xb, w1t, tab, qb, kb, vt);

    // Flash attention v14 (atomic-free split-K, max job 16 trips, LPT order)
    flash_attn<<<dim3(48 * BB * HH), 256, 0, stream>>>(qb, kb, vt, yb, pO, pL,
                                                       is_c, mask);

    // merge halves into y rows 1024..2047 per batch
    attn_merge<<<2048, 256, 0, stream>>>(pO, pL, yb);

    // GEMM2: out = y @ out_w  (M=4096, N=1024, K=1024), tile 128x64, dbuf,
    // 1D XCD-chunked grid: 512 blocks, nbx = 16.
    gemm_mfma<float, 64><<<(DD / 64) * (4096 / 128), 256, 0, stream>>>(
        yb, w2t, out, 4096, DD, DD, DD / 64);
}

// Round 13
// 193.722 us; speedup vs baseline: 1.1276x; 1.0115x over previous
//
#include <hip/hip_runtime.h>
#include <hip/hip_bf16.h>

// Problem constants (B=2, S=2048, D=1024, H=16, Dh=64) — I/O float32.
#define BB 2
#define SS 2048
#define DD 1024
#define HH 16
#define N3 3072

// split-K partial buffer geometry: [half][bh(32)][tile-16(16)][row(64)][d(64)]
#define POH (32 * 16 * 64 * 64)   // floats per half = 2,097,152
#define PLH (32 * 16 * 64)        // l floats per half = 32,768

typedef __attribute__((ext_vector_type(8))) short bf16x8;   // 8 bf16 in 4 VGPRs
typedef __attribute__((ext_vector_type(4))) float f32x4;
typedef __attribute__((ext_vector_type(2))) unsigned int u32x2;

__device__ __forceinline__ float b2f(unsigned short u) {
    return __uint_as_float(((unsigned int)u) << 16);
}
__device__ __forceinline__ unsigned short f2b(float f) {
    unsigned int x = __float_as_uint(f);
    x += 0x7fffu + ((x >> 16) & 1u);   // RNE
    return (unsigned short)(x >> 16);
}
__device__ __forceinline__ unsigned int pack2bf(float a, float b) {
    __hip_bfloat162 h = __float22bfloat162_rn(make_float2(a, b));  // v_cvt_pk_bf16_f32
    return *(unsigned int*)&h;
}

// async global->LDS, 16B/lane; LDS dest = wave-uniform base + lane*16.
__device__ __forceinline__ void gload_lds16(const void* g, void* l) {
    __builtin_amdgcn_global_load_lds(
        (__attribute__((address_space(1))) void*)g,
        (__attribute__((address_space(3))) void*)l, 16, 0, 0);
}

// ---------------------------------------------------------------------------
// Fused preprocessing (one dispatch, range-split):
//   [0, 4096)        : x fp32 -> xb bf16 (4 floats/thread)
//   [4096, 4864)     : qkv_w [1024][3072] -> w1t [3072][1024] cast+transpose
//   [4864, 5120)     : out_w [1024][1024] -> w2t cast+transpose
//   [5120, 5376)     : sincos table
// All four are independent (disjoint outputs, input-only reads); branch is
// block-uniform so the barrier in the transpose branch is safe.
// ---------------------------------------------------------------------------
__global__ __launch_bounds__(256) void prep(
    const float* __restrict__ x,
    const float* __restrict__ qkv_w,
    const float* __restrict__ out_w,
    unsigned short* __restrict__ xb,
    unsigned short* __restrict__ w1t,
    unsigned short* __restrict__ w2t,
    float2* __restrict__ tab)
{
    __shared__ unsigned short tile[64][66];
    const int bid = blockIdx.x;
    const int tid = threadIdx.x;

    if (bid < 4096) {
        // fp32 -> bf16 cast
        const int i = (bid * 256 + tid) * 4;
        float4 f = *(const float4*)(x + i);
        uint2 o;
        o.x = pack2bf(f.x, f.y);
        o.y = pack2bf(f.z, f.w);
        *(uint2*)(xb + i) = o;
        return;
    }

    const float* src;
    unsigned short* dst;
    int R, C, bx, by;
    if (bid < 4864) {
        const int t = bid - 4096;
        src = qkv_w; dst = w1t; R = DD; C = N3;
        bx = t % 48; by = t / 48;
    } else if (bid < 5120) {
        const int t = bid - 4864;
        src = out_w; dst = w2t; R = DD; C = DD;
        bx = t % 16; by = t / 16;
    } else {
        // sincos table
        const int i = (bid - 5120) * 256 + tid;   // SS*32 entries
        const int t = i & 31;
        const int s = i >> 5;
        float inv = powf(10000.0f, -(float)t * (1.0f / 32.0f));
        float sn, c;
        sincosf((float)s * inv, &sn, &c);
        tab[i] = make_float2(c, sn);
        return;
    }

    // cast + transpose, 64x64 tile
    const int c0 = bx * 64, r0 = by * 64;
    const int lr = tid >> 4;
    const int lc = (tid & 15) * 4;
    #pragma unroll
    for (int i = 0; i < 4; ++i) {
        float4 f = *(const float4*)(src + (size_t)(r0 + lr + i * 16) * C + c0 + lc);
        tile[lr + i * 16][lc + 0] = f2b(f.x);
        tile[lr + i * 16][lc + 1] = f2b(f.y);
        tile[lr + i * 16][lc + 2] = f2b(f.z);
        tile[lr + i * 16][lc + 3] = f2b(f.w);
    }
    __syncthreads();
    #pragma unroll
    for (int i = 0; i < 4; ++i) {
        const int wr = lr + i * 16;
        ushort4 o;
        o.x = tile[lc + 0][wr];
        o.y = tile[lc + 1][wr];
        o.z = tile[lc + 2][wr];
        o.w = tile[lc + 3][wr];
        *(ushort4*)(dst + (size_t)(c0 + wr) * R + r0 + lc) = o;
    }
}

// ---------------------------------------------------------------------------
// GEMM1 + fused RoPE/split/V-transpose epilogue (dbuf + XCD 1D decode).
// C = xb @ w1t^T (M=4096, N=3072, K=1024), tile 128x128. With TN=128 each
// wave's 64-col output window is 64-aligned -> exactly ONE head and ONE
// section (q/k/v). Lane holds both rotation partners: d = ni*16+l16 in
// acc[mi][ni], d+32 in acc[mi][ni+2] (ni<2). Rotate from f32 accumulators,
// scale q by 0.125*log2e, store q,k -> [B,H,S,64]; v -> vt [B,H,64,S].
// ---------------------------------------------------------------------------
__global__ __launch_bounds__(256) void gemm_qkv_rope(
    const unsigned short* __restrict__ A,     // xb [4096][1024]
    const unsigned short* __restrict__ Bt,    // w1t [3072][1024]
    const float2* __restrict__ tab,
    unsigned short* __restrict__ qo,
    unsigned short* __restrict__ ko,
    unsigned short* __restrict__ vt)
{
    constexpr int K = DD;
    constexpr int nbx = N3 / 128;              // 24
    __shared__ unsigned short Al[2][128 * 32];
    __shared__ unsigned short Bl[2][128 * 32];
    const int tid  = threadIdx.x;
    const int wave = tid >> 6;
    const int lane = tid & 63;
    const int quad = lane >> 4;
    const int l16  = lane & 15;

    const int per = gridDim.x >> 3;
    const int idx = (blockIdx.x & 7) * per + (blockIdx.x >> 3);
    const int m0 = (idx / nbx) * 128;
    const int n0 = (idx % nbx) * 128;
    const int wm = (wave >> 1) * 64;
    const int wn = (wave & 1) * 64;

    const int srow = wave * 32 + (lane >> 2);
    const int scol = (lane & 3) * 8;
    const unsigned short* gA = A  + (size_t)(m0 + srow) * K + scol;
    const unsigned short* gB = Bt + (size_t)(n0 + srow) * K + scol;

    f32x4 acc[4][4];
    #pragma unroll
    for (int mi = 0; mi < 4; ++mi)
        #pragma unroll
        for (int ni = 0; ni < 4; ++ni)
            acc[mi][ni] = (f32x4){0.f, 0.f, 0.f, 0.f};

    auto stage = [&](int k0, int buf) {
        #pragma unroll
        for (int i = 0; i < 2; ++i) {
            gload_lds16(gA + (size_t)i * 16 * K + k0, Al[buf] + (wave * 2 + i) * 512);
            gload_lds16(gB + (size_t)i * 16 * K + k0, Bl[buf] + (wave * 2 + i) * 512);
        }
    };

    stage(0, 0);
    int cur = 0;
    for (int k0 = 0; k0 < K; k0 += 32) {
        __syncthreads();                       // stage(cur) visible; prev reads done
        if (k0 + 32 < K) stage(k0 + 32, cur ^ 1);

        bf16x8 af[4], bfr[4];
        #pragma unroll
        for (int mi = 0; mi < 4; ++mi)
            af[mi] = *(const bf16x8*)&Al[cur][(wm + mi * 16 + l16) * 32 + quad * 8];
        #pragma unroll
        for (int ni = 0; ni < 4; ++ni)
            bfr[ni] = *(const bf16x8*)&Bl[cur][(wn + ni * 16 + l16) * 32 + quad * 8];
        #pragma unroll
        for (int mi = 0; mi < 4; ++mi)
            #pragma unroll
            for (int ni = 0; ni < 4; ++ni)
                acc[mi][ni] = __builtin_amdgcn_mfma_f32_16x16x32_bf16(
                    af[mi], bfr[ni], acc[mi][ni], 0, 0, 0);
        cur ^= 1;
    }

    // fused epilogue
    const int gc  = n0 + wn;                 // 64-aligned global col base
    const int sec = gc >> 10;                // 0=q, 1=k, 2=v
    const int h   = (gc & 1023) >> 6;
    const int s0g = m0 + wm;
    const int b   = s0g >> 11;               // batch
    const size_t bh = (size_t)b * HH + h;

    if (sec < 2) {
        const float SCq = (sec == 0) ? 0.18033688011112042f : 1.0f;  // 0.125*log2e on q
        unsigned short* dst = (sec == 0) ? qo : ko;
        #pragma unroll
        for (int mi = 0; mi < 4; ++mi) {
            #pragma unroll
            for (int r = 0; r < 4; ++r) {
                const int ss = (s0g + mi * 16 + quad * 4 + r) & (SS - 1);
                const float2* tp = tab + (size_t)ss * 32;
                unsigned short* row = dst + (bh * SS + ss) * 64;
                #pragma unroll
                for (int ni = 0; ni < 2; ++ni) {
                    const int t = ni * 16 + l16;       // d < 32, freq index
                    float2 cs = tp[t];                 // coalesced over l16
                    const float x1 = acc[mi][ni][r];
                    const float x2 = acc[mi][ni + 2][r];
                    row[t]      = f2b((x1 * cs.x - x2 * cs.y) * SCq);
                    row[t + 32] = f2b((x1 * cs.y + x2 * cs.x) * SCq);
                }
            }
        }
    } else {
        #pragma unroll
        for (int mi = 0; mi < 4; ++mi) {
            const int ss0 = (s0g + mi * 16 + quad * 4) & (SS - 1);
            #pragma unroll
            for (int ni = 0; ni < 4; ++ni) {
                const int d = ni * 16 + l16;
                ushort4 o;
                o.x = f2b(acc[mi][ni][0]);
                o.y = f2b(acc[mi][ni][1]);
                o.z = f2b(acc[mi][ni][2]);
                o.w = f2b(acc[mi][ni][3]);
                *(ushort4*)(vt + (bh * 64 + d) * SS + ss0) = o;   // 8B aligned
            }
        }
    }
}

// ---------------------------------------------------------------------------
// GEMM2: out = y @ out_w  (M=4096, N=1024, K=1024), f32 out. Tile 64x64,
// 4 waves (each 32x32), dbuf staging, 1D XCD-chunked decode.
// 1024 blocks -> 4 blocks/CU (vs 2 at tile 128x64); LDS 16 KB.
// ---------------------------------------------------------------------------
__global__ __launch_bounds__(256) void gemm_out(
    const unsigned short* __restrict__ A,    // yb bf16 [4096][1024]
    const unsigned short* __restrict__ Bt,   // w2t bf16 [1024][1024]
    float* __restrict__ C)                   // out f32 [4096][1024]
{
    constexpr int K = DD;
    constexpr int nbx = DD / 64;             // 16
    __shared__ unsigned short Al[2][64 * 32];
    __shared__ unsigned short Bl[2][64 * 32];
    const int tid  = threadIdx.x;
    const int wave = tid >> 6;
    const int lane = tid & 63;
    const int quad = lane >> 4;
    const int l16  = lane & 15;

    const int per = gridDim.x >> 3;
    const int idx = (blockIdx.x & 7) * per + (blockIdx.x >> 3);
    const int m0 = (idx / nbx) * 64;
    const int n0 = (idx % nbx) * 64;
    const int wm = (wave >> 1) * 32;
    const int wn = (wave & 1) * 32;

    // per-wave staging: 64 lanes x 16B = 16 rows x 32 cols (lane*8 shorts)
    const int srow = wave * 16 + (lane >> 2);
    const int scol = (lane & 3) * 8;
    const unsigned short* gA = A  + (size_t)(m0 + srow) * K + scol;
    const unsigned short* gB = Bt + (size_t)(n0 + srow) * K + scol;

    f32x4 acc[2][2];
    #pragma unroll
    for (int mi = 0; mi < 2; ++mi)
        #pragma unroll
        for (int ni = 0; ni < 2; ++ni)
            acc[mi][ni] = (f32x4){0.f, 0.f, 0.f, 0.f};

    auto stage = [&](int k0, int buf) {
        gload_lds16(gA + k0, Al[buf] + wave * 512);
        gload_lds16(gB + k0, Bl[buf] + wave * 512);
    };

    stage(0, 0);
    int cur = 0;
    for (int k0 = 0; k0 < K; k0 += 32) {
        __syncthreads();                     // stage(cur) visible; prev reads done
        if (k0 + 32 < K) stage(k0 + 32, cur ^ 1);

        bf16x8 af[2], bfr[2];
        #pragma unroll
        for (int mi = 0; mi < 2; ++mi)
            af[mi] = *(const bf16x8*)&Al[cur][(wm + mi * 16 + l16) * 32 + quad * 8];
        #pragma unroll
        for (int ni = 0; ni < 2; ++ni)
            bfr[ni] = *(const bf16x8*)&Bl[cur][(wn + ni * 16 + l16) * 32 + quad * 8];
        #pragma unroll
        for (int mi = 0; mi < 2; ++mi)
            #pragma unroll
            for (int ni = 0; ni < 2; ++ni)
                acc[mi][ni] = __builtin_amdgcn_mfma_f32_16x16x32_bf16(
                    af[mi], bfr[ni], acc[mi][ni], 0, 0, 0);
        cur ^= 1;
    }

    #pragma unroll
    for (int mi = 0; mi < 2; ++mi) {
        #pragma unroll
        for (int r = 0; r < 4; ++r) {
            const size_t base = (size_t)(m0 + wm + mi * 16 + quad * 4 + r) * DD + n0 + wn;
            #pragma unroll
            for (int ni = 0; ni < 2; ++ni)
                C[base + ni * 16 + l16] = acc[mi][ni][r];
        }
    }
}

// ---------------------------------------------------------------------------
// One 64-key attention step (v9 math): max-free softmax (P = exp2(S) directly,
// normalization cancels the row scale exactly) + in-register P redistribution
// via permlane32/16 swaps + ones-MFMA l reduction. T5 setprio around the MFMA
// clusters (independent blocks at different phases -> scheduler can arbitrate).
// ---------------------------------------------------------------------------
__device__ __forceinline__ void attn_step(
    const unsigned short* __restrict__ Kb,   // K tile [key][64], swizzled
    const unsigned short* __restrict__ Vb,   // V^T tile [d][64], swizzled
    const bf16x8 qf0, const bf16x8 qf1, const bf16x8 onesf,
    f32x4 O[4], f32x4& l_acc,
    bool diag, const unsigned char* mrow,    // mrow != nullptr => non-causal mask
    int kt, int quad, int l16, int csw, int qg)
{
    // S^T = K·Q^T : 4 key-subtiles (scale folded into q)
    f32x4 Sf[4];
    __builtin_amdgcn_s_setprio(1);
    #pragma unroll
    for (int st = 0; st < 4; ++st) {
        const unsigned short* kr = &Kb[(st * 16 + l16) * 64];
        bf16x8 kf0 = *(const bf16x8*)(kr + csw * 8);
        bf16x8 kf1 = *(const bf16x8*)(kr + (csw ^ 4) * 8);
        f32x4 s = (f32x4){0.f, 0.f, 0.f, 0.f};
        s = __builtin_amdgcn_mfma_f32_16x16x32_bf16(kf0, qf0, s, 0, 0, 0);
        s = __builtin_amdgcn_mfma_f32_16x16x32_bf16(kf1, qf1, s, 0, 0, 0);
        Sf[st] = s;
    }
    __builtin_amdgcn_s_setprio(0);

    if (diag) {
        #pragma unroll
        for (int st = 0; st < 4; ++st) {
            const int kb0 = kt * 64 + st * 16 + quad * 4;
            #pragma unroll
            for (int r = 0; r < 4; ++r)
                if (kb0 + r > qg) Sf[st][r] = -1e30f;
        }
    } else if (mrow) {
        #pragma unroll
        for (int st = 0; st < 4; ++st) {
            uchar4 mv = *(const uchar4*)(mrow + st * 16 + quad * 4);
            if (!mv.x) Sf[st][0] = -1e30f;
            if (!mv.y) Sf[st][1] = -1e30f;
            if (!mv.z) Sf[st][2] = -1e30f;
            if (!mv.w) Sf[st][3] = -1e30f;
        }
    }

    // P = exp2(S) directly (masked lanes -> exp2(-1e30) = 0)
    #pragma unroll
    for (int st = 0; st < 4; ++st)
        #pragma unroll
        for (int r = 0; r < 4; ++r)
            Sf[st][r] = exp2f(Sf[st][r]);

    // pack: W[st][j] = bf16 pair of keys (st*16+quad*4+2j, +1)
    unsigned int W[4][2];
    #pragma unroll
    for (int st = 0; st < 4; ++st) {
        W[st][0] = pack2bf(Sf[st][0], Sf[st][1]);
        W[st][1] = pack2bf(Sf[st][2], Sf[st][3]);
    }

    // in-register quad exchange -> PV B-operand fragments
    unsigned int pw0[4], pw1[4];
    #pragma unroll
    for (int j = 0; j < 2; ++j) {
        u32x2 s1 = __builtin_amdgcn_permlane32_swap(W[0][j], W[1][j], false, false);
        u32x2 s2 = __builtin_amdgcn_permlane16_swap(s1.x, s1.y, false, false);
        pw0[j]     = s2.x;
        pw0[j + 2] = s2.y;
        u32x2 t1 = __builtin_amdgcn_permlane32_swap(W[2][j], W[3][j], false, false);
        u32x2 t2 = __builtin_amdgcn_permlane16_swap(t1.x, t1.y, false, false);
        pw1[j]     = t2.x;
        pw1[j + 2] = t2.y;
    }
    bf16x8 pf0 = *(const bf16x8*)pw0;
    bf16x8 pf1 = *(const bf16x8*)pw1;

    // l += 1^T · P^T ; O^T += V^T·P^T  (matrix pipe)
    __builtin_amdgcn_s_setprio(1);
    l_acc = __builtin_amdgcn_mfma_f32_16x16x32_bf16(onesf, pf0, l_acc, 0, 0, 0);
    l_acc = __builtin_amdgcn_mfma_f32_16x16x32_bf16(onesf, pf1, l_acc, 0, 0, 0);
    #pragma unroll
    for (int st = 0; st < 4; ++st) {
        const unsigned short* vr = &Vb[(st * 16 + l16) * 64];
        bf16x8 vf0 = *(const bf16x8*)(vr + csw * 8);
        bf16x8 vf1 = *(const bf16x8*)(vr + (csw ^ 4) * 8);
        O[st] = __builtin_amdgcn_mfma_f32_16x16x32_bf16(vf0, pf0, O[st], 0, 0, 0);
        O[st] = __builtin_amdgcn_mfma_f32_16x16x32_bf16(vf1, pf1, O[st], 0, 0, 0);
    }
    __builtin_amdgcn_s_setprio(0);
}

// ---------------------------------------------------------------------------
// Flash attention v14: ATOMIC-FREE split-K. Max-free softmax makes partials
// exactly additive, and each split tile has exactly TWO jobs (A-half keys
// 0..15, B-half keys 16..tile) -> each half writes its own disjoint partial
// buffer with plain coalesced f32x4 stores; no atomics, no zeroing pass.
// Per (b,h): 48 jobs, MAX JOB = 16 trips (halves the per-CU makespan vs the
// 32-trip monolithic tile). LPT issue order inside XCD chunks; 1536 blocks,
// LDS 32 KB -> 5 resident blocks/CU + backfill. v9 per-step math + T5 setprio.
// q,k: [B,H,S,64] bf16 (q pre-scaled); vt: [B,H,64,S] bf16; y: [B,S,H*64] bf16.
// ---------------------------------------------------------------------------
__global__ __launch_bounds__(256) void flash_attn(
    const unsigned short* __restrict__ q,
    const unsigned short* __restrict__ k,
    const unsigned short* __restrict__ vt,
    unsigned short* __restrict__ y,
    float* __restrict__ pO,                  // [2][bh][tile-16][row64][d64] f32
    float* __restrict__ pL,                  // [2][bh][tile-16][row64] f32
    const int* __restrict__ is_causal,
    const unsigned char* __restrict__ attn_mask)
{
    __shared__ unsigned short Kl[2][64 * 64];
    __shared__ unsigned short Vl[2][64 * 64];

    // XCD chunk = 192 consecutive works = 4 (b,h) x 48 jobs, LPT order.
    const int bid  = blockIdx.x;                   // 0..1535
    const int work = (bid & 7) * 192 + (bid >> 3);
    const int bhi  = work / 48;                    // 0..31 = b*16+h
    const int s    = work % 48;                    // job slot, descending trips
    const int b = bhi >> 4;
    const int h = bhi & 15;
    const bool causal = (is_causal[0] != 0);

    // job decode: s<16 -> A-half of tile 16+s (keys 0..15, 16 trips).
    // s>=16, r=s-16, p=r>>1: r odd -> whole tile 15-p; r even -> B-half of
    // tile 31-p (keys 16..tile). Descending-trip issue order.
    int tile, k0t, k1t;
    bool split;
    if (s < 16) {
        tile = 16 + s; k0t = 0; k1t = 15; split = true;
    } else {
        const int r = s - 16, p = r >> 1;
        if (r & 1) { tile = 15 - p; k0t = 0;  k1t = causal ? tile : 31; split = false; }
        else       { tile = 31 - p; k0t = 16; k1t = causal ? tile : 31; split = true;  }
    }
    const int half = (s < 16) ? 0 : 1;             // A-partials : B-partials

    const int tid  = threadIdx.x;
    const int wave = tid >> 6;
    const int lane = tid & 63;
    const int quad = lane >> 4;
    const int l16  = lane & 15;

    const size_t bh = (size_t)b * HH + h;

    const int qg = tile * 64 + wave * 16 + l16;
    const unsigned short* qrow = q + (bh * SS + qg) * 64;
    const bf16x8 qf0 = *(const bf16x8*)(qrow + quad * 8);
    const bf16x8 qf1 = *(const bf16x8*)(qrow + 32 + quad * 8);

    bf16x8 onesf;
    #pragma unroll
    for (int i = 0; i < 8; ++i) onesf[i] = (short)0x3F80;   // bf16 1.0

    const unsigned short* kbase  = k  + bh * SS * 64;   // [key][d]
    const unsigned short* vtbase = vt + bh * 64 * SS;   // [d][s]

    const int Rl  = lane >> 3;
    const int cph = lane & 7;
    const int csw = quad ^ (l16 & 7);

    f32x4 O[4];
    #pragma unroll
    for (int st = 0; st < 4; ++st) O[st] = (f32x4){0.f, 0.f, 0.f, 0.f};
    f32x4 l_acc = (f32x4){0.f, 0.f, 0.f, 0.f};

    // stage K/V tile kt into buffer kt&1 (4 issues per wave)
    auto stage = [&](int kt) {
        const int buf = kt & 1;
        #pragma unroll
        for (int i = 0; i < 2; ++i) {
            const int jj = wave * 2 + i;
            const int R  = jj * 8 + Rl;
            const int cl = cph ^ (R & 7);
            gload_lds16(kbase + ((size_t)(kt * 64 + R) * 64 + cl * 8),
                        &Kl[buf][jj * 512]);
            gload_lds16(vtbase + ((size_t)R * SS + kt * 64 + cl * 8),
                        &Vl[buf][jj * 512]);
        }
    };

    stage(k0t);
    for (int kt = k0t; kt <= k1t; ++kt) {
        __syncthreads();                     // stage(kt) visible; prev reads done
        if (kt + 1 <= k1t) stage(kt + 1);    // prefetch into other buffer

        const unsigned char* mrow = causal ? nullptr
                                           : (attn_mask + (size_t)b * SS + kt * 64);
        attn_step(Kl[kt & 1], Vl[kt & 1], qf0, qf1, onesf, O, l_acc,
                  causal && kt == tile, mrow, kt, quad, l16, csw, qg);
    }

    if (!split) {
        // whole-tile job: l_acc fully reduced; normalize and store bf16.
        const float inv = 1.0f / l_acc[0];
        unsigned short* yrow = y + ((size_t)b * SS + qg) * DD + h * 64;
        #pragma unroll
        for (int st = 0; st < 4; ++st) {
            uint2 o;
            o.x = pack2bf(O[st][0] * inv, O[st][1] * inv);
            o.y = pack2bf(O[st][2] * inv, O[st][3] * inv);
            *(uint2*)(yrow + st * 16 + quad * 4) = o;
        }
    } else {
        // split job: plain stores into this half's disjoint partial buffer.
        float* ob = pO + (size_t)half * POH
                  + (((bh * 16 + (size_t)(tile - 16)) * 64 + wave * 16 + l16) * 64);
        #pragma unroll
        for (int st = 0; st < 4; ++st)
            *(f32x4*)(ob + st * 16 + quad * 4) = O[st];
        if (quad == 0)
            pL[(size_t)half * PLH + (bh * 16 + (size_t)(tile - 16)) * 64
               + wave * 16 + l16] = l_acc[0];
    }
}

// ---------------------------------------------------------------------------
// Merge split-K halves: y rows of tiles 16..31 = (O_A+O_B)/(l_A+l_B), bf16.
// One thread per 4 floats of a half (2,097,152 floats -> 2048 blocks x 256).
// ---------------------------------------------------------------------------
__global__ __launch_bounds__(256) void attn_merge(
    const float* __restrict__ pO, const float* __restrict__ pL,
    unsigned short* __restrict__ y)
{
    const int i = (blockIdx.x * 256 + threadIdx.x) * 4;
    float4 oa = *(const float4*)(pO + i);
    float4 obv = *(const float4*)(pO + POH + i);
    const int rowi = i >> 6;            // (bh*16+tt)*64 + row
    const int d    = i & 63;
    const float inv = 1.0f / (pL[rowi] + pL[PLH + rowi]);
    const int row = rowi & 63;
    const int tt  = (rowi >> 6) & 15;
    const int bh  = rowi >> 10;
    const int b = bh >> 4, h = bh & 15;
    const int sq = (16 + tt) * 64 + row;
    unsigned short* yp = y + ((size_t)b * SS + sq) * DD + h * 64 + d;
    uint2 ov;
    ov.x = pack2bf((oa.x + obv.x) * inv, (oa.y + obv.y) * inv);
    ov.y = pack2bf((oa.z + obv.z) * inv, (oa.w + obv.w) * inv);
    *(uint2*)yp = ov;
}

// ---------------------------------------------------------------------------
// Workspace: xb/yb (aliased) | w1t | w2t | pO/pL (old qkv region) | qb | kb |
// vt | tab. ~67.6 MB. 5 dispatches total.
// ---------------------------------------------------------------------------
extern "C" void kernel_launch(void* const* d_in, const int* in_sizes, int n_in,
                              void* d_out, int out_size, void* d_ws, size_t ws_size,
                              hipStream_t stream) {
    const float* x      = (const float*)d_in[0];
    const float* qkv_w  = (const float*)d_in[1];
    const float* out_w  = (const float*)d_in[2];
    const unsigned char* mask = (const unsigned char*)d_in[3];
    const int*   is_c   = (const int*)d_in[4];
    float* out = (float*)d_out;

    unsigned short* xb  = (unsigned short*)d_ws;             // aliased with yb
    unsigned short* w1t = xb  + (size_t)4096 * 1024;
    unsigned short* w2t = w1t + (size_t)3072 * 1024;
    unsigned short* qkv = w2t + (size_t)1024 * 1024;         // region: pO/pL
    unsigned short* qb  = qkv + (size_t)4096 * 3072;
    unsigned short* kb  = qb  + (size_t)BB * HH * SS * 64;
    unsigned short* vt  = kb  + (size_t)BB * HH * SS * 64;
    float2* tab = (float2*)(vt + (size_t)BB * HH * SS * 64);
    unsigned short* yb = xb;   // x dead after GEMM1

    // split-K partials in the old qkv region:
    // 2*POH + 2*PLH floats = 17.0 MB < 25.2 MB available.
    float* pO = (float*)qkv;                 // [2][POH]
    float* pL = pO + (size_t)2 * POH;        // [2][PLH]

    // fused preprocessing: cast + 2 transposes + sincos, one dispatch
    prep<<<5376, 256, 0, stream>>>(x, qkv_w, out_w, xb, w1t, w2t, tab);

    // GEMM1 + fused RoPE/split/V-transpose (dbuf, XCD-chunked 1D grid)
    gemm_qkv_rope<<<(N3 / 128) * (4096 / 128), 256, 0, stream>>>(
        xb, w1t, tab, qb, kb, vt);

    // Flash attention v14 (atomic-free split-K, max job 16 trips, LPT order)
    flash_attn<<<dim3(48 * BB * HH), 256, 0, stream>>>(qb, kb, vt, yb, pO, pL,
                                                       is_c, mask);

    // merge halves into y rows 1024..2047 per batch
    attn_merge<<<2048, 256, 0, stream>>>(pO, pL, yb);

    // GEMM2: 64x64 tile, 1024 blocks = 4/CU, dbuf, XCD-chunked
    gemm_out<<<1024, 256, 0, stream>>>(yb, w2t, out);
}